// Round 5
// baseline (299.914 us; speedup 1.0000x reference)
//
#include <hip/hip_runtime.h>
#include <hip/hip_bf16.h>

// AttentionBlock3D: GroupNorm(8,256) -> QKV 1x1 conv -> 8-head attn (n=4096, d=64) -> out proj -> +x
// R5: attn = 1-wave blocks, 64q/wave, kv-split x2 (additive under fixed-max softmax),
//     barrier-free counted-vmcnt double-buffer pipeline, bf16 pk-atomic combine + norm pass.

typedef __attribute__((ext_vector_type(8))) short bf8_t;     // 8 bf16
typedef __attribute__((ext_vector_type(4))) float f4_t;      // 16x16 C/D frag
typedef __attribute__((ext_vector_type(16))) float f16v;     // 32x32 C/D frag

#define NTOK 4096
#define GRP_ELEMS (32 * 4096)

__device__ __forceinline__ unsigned short f2bf(float f) {
  union { float f; unsigned int i; } v; v.f = f;
  unsigned int r = v.i + 0x7fffu + ((v.i >> 16) & 1u);   // RNE
  return (unsigned short)(r >> 16);
}

__device__ __forceinline__ unsigned int pkbf(float a, float b) {
  float2 t; t.x = a; t.y = b;
  __hip_bfloat162 h = __float22bfloat162_rn(t);
  union { __hip_bfloat162 h; unsigned int u; } c; c.h = h;
  return c.u;
}

__device__ __forceinline__ __hip_bfloat162 bf2(float a, float b) {
  float2 t; t.x = a; t.y = b;
  return __float22bfloat162_rn(t);
}

__device__ __forceinline__ void gl_lds16(const unsigned short* g, unsigned short* l) {
  __builtin_amdgcn_global_load_lds((const __attribute__((address_space(1))) void*)g,
                                   (__attribute__((address_space(3))) void*)l, 16, 0, 0);
}

// swizzled 16B LDS read; 128B-stride rows: slot ^= row&7
__device__ __forceinline__ bf8_t ldsw128(const unsigned short* base, int row, int du) {
  return *(const bf8_t*)((const char*)base + (((row << 7) + (du << 4)) ^ ((row & 7) << 4)));
}
// 64B-stride rows: slot ^= (row>>1)&3
__device__ __forceinline__ bf8_t ldsw64(const unsigned short* base, int row, int du) {
  return *(const bf8_t*)((const char*)base + (((row << 6) + (du << 4)) ^ (((row >> 1) & 3) << 4)));
}

#if __has_builtin(__builtin_amdgcn_exp2f)
#define EXP2 __builtin_amdgcn_exp2f
#else
#define EXP2 exp2f
#endif

#define LGKM0() do { asm volatile("s_waitcnt lgkmcnt(0)" ::: "memory"); \
                     __builtin_amdgcn_sched_barrier(0); } while (0)
#define WAITVM8() asm volatile("s_waitcnt vmcnt(8)" ::: "memory")
#define WAITVM0() asm volatile("s_waitcnt vmcnt(0)" ::: "memory")

// ---------------- GroupNorm stats (blocks 0..255) + weight cast (blocks 256..767) ----------------
__global__ __launch_bounds__(256) void gn_stats_castw(const float* __restrict__ x, float* __restrict__ stats,
    const float* __restrict__ wqkv, const float* __restrict__ wout,
    unsigned short* __restrict__ wq, unsigned short* __restrict__ wo) {
  int bid = blockIdx.x;
  if (bid >= 256) {
    int i = (bid - 256) * 256 + threadIdx.x;
    const float* src; unsigned short* dst; int off;
    if (i < 98304) { src = wqkv; dst = wq; off = i; }
    else           { src = wout; dst = wo; off = i - 98304; }
    float4 v = ((const float4*)src)[off];
    union { unsigned short s[4]; uint2 u; } o;
    o.s[0] = f2bf(v.x); o.s[1] = f2bf(v.y); o.s[2] = f2bf(v.z); o.s[3] = f2bf(v.w);
    *(uint2*)(dst + (size_t)off * 4) = o.u;
    return;
  }
  int g = bid & 15, sp = bid >> 4;
  const float4* p = (const float4*)(x + (size_t)g * GRP_ELEMS + (size_t)sp * 8192);
  float s = 0.f, s2 = 0.f;
  for (int i = threadIdx.x; i < 2048; i += 256) {
    float4 v = p[i];
    s  += v.x + v.y + v.z + v.w;
    s2 += v.x * v.x + v.y * v.y + v.z * v.z + v.w * v.w;
  }
  for (int m = 32; m; m >>= 1) { s += __shfl_xor(s, m); s2 += __shfl_xor(s2, m); }
  __shared__ float rs[4][2];
  int wv = threadIdx.x >> 6;
  if ((threadIdx.x & 63) == 0) { rs[wv][0] = s; rs[wv][1] = s2; }
  __syncthreads();
  if (threadIdx.x == 0) {
    float ts = rs[0][0] + rs[1][0] + rs[2][0] + rs[3][0];
    float t2 = rs[0][1] + rs[1][1] + rs[2][1] + rs[3][1];
    atomicAdd(&stats[g], ts);
    atomicAdd(&stats[16 + g], t2);
  }
}

// ---------------- GroupNorm apply + transpose to XN^T[b][n][c] bf16 ----------------
__global__ __launch_bounds__(256) void gn_apply(const float* __restrict__ x,
    const float* __restrict__ gamma, const float* __restrict__ beta,
    const float* __restrict__ stats, unsigned short* __restrict__ xnt) {
  __shared__ float t[64][65];
  int b = blockIdx.z, c0 = blockIdx.y * 64, n0 = blockIdx.x * 64;
  int tr = threadIdx.x >> 2;
  int tc = (threadIdx.x & 3) * 16;
  int c = c0 + tr;
  int g = b * 8 + (c >> 5);
  float mu = stats[g] * (1.f / GRP_ELEMS);
  float var = stats[16 + g] * (1.f / GRP_ELEMS) - mu * mu;
  float rstd = rsqrtf(var + 1e-5f);
  float sc = gamma[c] * rstd;
  float sh = beta[c] - mu * sc;
  const float* xp = x + ((size_t)(b * 256 + c)) * NTOK + n0 + tc;
  for (int q = 0; q < 4; ++q) {
    float4 v = *(const float4*)(xp + q * 4);
    t[tr][tc + q * 4 + 0] = v.x * sc + sh;
    t[tr][tc + q * 4 + 1] = v.y * sc + sh;
    t[tr][tc + q * 4 + 2] = v.z * sc + sh;
    t[tr][tc + q * 4 + 3] = v.w * sc + sh;
  }
  __syncthreads();
  int n = n0 + tr;
  union { unsigned short s[16]; uint4 u[2]; } tmp;
  for (int q = 0; q < 16; ++q) tmp.s[q] = f2bf(t[tc + q][tr]);
  uint4* dst = (uint4*)(xnt + ((size_t)b * NTOK + n) * 256 + c0 + tc);
  dst[0] = tmp.u[0];
  dst[1] = tmp.u[1];
}

// ---------------- QKV GEMM: M=1536 K=256 N=4096, 128x128 tile, BK=32, dbuf gload_lds ----------------
__global__ __launch_bounds__(256) void qkv_gemm(const unsigned short* __restrict__ wq,
    const unsigned short* __restrict__ xnt, const float* __restrict__ bqkv,
    unsigned short* __restrict__ Qg, unsigned short* __restrict__ Kg, unsigned short* __restrict__ Vt) {
  __shared__ unsigned short Al[2][4096];
  __shared__ unsigned short Bl[2][4096];
  int b = blockIdx.z, m0 = blockIdx.y * 128, n0 = blockIdx.x * 128;
  const unsigned short* Ap = wq + (size_t)m0 * 256;
  const unsigned short* Bp = xnt + ((size_t)b * NTOK + n0) * 256;
  int lane = threadIdx.x & 63, wv = threadIdx.x >> 6;
  int lq = lane & 15, hq = lane >> 4;
  int m_off = (wv >> 1) * 64, n_off = (wv & 1) * 64;
  f4_t acc[4][4] = {};
  {
    for (int is = 0; is < 2; ++is) {
      int ck = wv * 128 + is * 64 + lane;
      int r = ck >> 2, cu = ck & 3;
      int csw = (cu ^ ((r >> 1) & 3)) << 3;
      gl_lds16(Ap + (size_t)r * 256 + csw, &Al[0][(wv * 128 + is * 64) * 8]);
      gl_lds16(Bp + (size_t)r * 256 + csw, &Bl[0][(wv * 128 + is * 64) * 8]);
    }
  }
  __syncthreads();
  for (int kt = 0; kt < 8; ++kt) {
    int cb = kt & 1, nb = cb ^ 1;
    if (kt < 7) {
      int k0 = (kt + 1) * 32;
      for (int is = 0; is < 2; ++is) {
        int ck = wv * 128 + is * 64 + lane;
        int r = ck >> 2, cu = ck & 3;
        int csw = (cu ^ ((r >> 1) & 3)) << 3;
        gl_lds16(Ap + (size_t)r * 256 + k0 + csw, &Al[nb][(wv * 128 + is * 64) * 8]);
        gl_lds16(Bp + (size_t)r * 256 + k0 + csw, &Bl[nb][(wv * 128 + is * 64) * 8]);
      }
    }
    const unsigned short* Ac = Al[cb];
    const unsigned short* Bc = Bl[cb];
    bf8_t af[4], bfr[4];
    for (int i = 0; i < 4; ++i) af[i]  = ldsw64(Ac, m_off + i * 16 + lq, hq);
    for (int j = 0; j < 4; ++j) bfr[j] = ldsw64(Bc, n_off + j * 16 + lq, hq);
    for (int i = 0; i < 4; ++i)
      for (int j = 0; j < 4; ++j)
        acc[i][j] = __builtin_amdgcn_mfma_f32_16x16x32_bf16(af[i], bfr[j], acc[i][j], 0, 0, 0);
    __syncthreads();
  }
  int tq = m0 >> 9;   // block-uniform: 0=Q,1=K,2=V
  if (tq < 2) {
    unsigned short* dst = tq == 0 ? Qg : Kg;
    float sc = tq == 0 ? 0.1803368801111243f : 1.0f;  // 1/8 * log2(e) folded for exp2 softmax
    for (int i = 0; i < 4; ++i)
      for (int j = 0; j < 4; ++j) {
        int o0 = m0 + m_off + i * 16 + hq * 4;
        int n = n0 + n_off + j * 16 + lq;
        int h = (o0 >> 6) & 7, dd0 = o0 & 63;
        size_t bh = (size_t)b * 8 + h;
        uint2 pk;
        pk.x = pkbf((acc[i][j][0] + bqkv[o0 + 0]) * sc, (acc[i][j][1] + bqkv[o0 + 1]) * sc);
        pk.y = pkbf((acc[i][j][2] + bqkv[o0 + 2]) * sc, (acc[i][j][3] + bqkv[o0 + 3]) * sc);
        *(uint2*)(dst + (bh * NTOK + n) * 64 + dd0) = pk;
      }
  } else {
    for (int i = 0; i < 4; ++i)
      for (int j = 0; j < 4; ++j) {
        int n = n0 + n_off + j * 16 + lq;
        for (int jj = 0; jj < 4; ++jj) {
          int o = m0 + m_off + i * 16 + hq * 4 + jj;
          int h = (o >> 6) & 7, dd = o & 63;
          size_t bh = (size_t)b * 8 + h;
          Vt[(bh * 64 + dd) * NTOK + n] = f2bf(acc[i][j][jj] + bqkv[o]);  // V^T [d][n]
        }
      }
  }
}

// ---------------- Flash attention: 1 wave/block, 64 q, kv-half 2048, tiles of 32, no barriers ----------------
__global__ __launch_bounds__(64, 2) void attn(const unsigned short* __restrict__ Qg,
    const unsigned short* __restrict__ Kg, const unsigned short* __restrict__ Vt,
    __hip_bfloat162* __restrict__ att, float* __restrict__ lsum) {
  __shared__ unsigned short Kls[2][2048];   // 32 kv x 64 d, swizzled, 4KB each
  __shared__ unsigned short Vls[2][2048];   // 64 d x 32 kv, swizzled, 4KB each
  int bid = blockIdx.x;
  // bid = qt*32 + j*8 + xcd ; combo = xcd*4 + j -> (half, bh): 4 x 512KB K/V per XCD (2MB < L2)
  int qt = bid >> 5, j = (bid >> 3) & 3, xcd = bid & 7;
  int combo = xcd * 4 + j;
  int half = combo >> 4, bh = combo & 15;
  int q0 = qt * 64;
  int b = bh >> 3, h = bh & 7;
  int kvbase = half * 2048;
  const unsigned short* kp = Kg + (size_t)bh * NTOK * 64;
  const unsigned short* vp = Vt + (size_t)bh * 64 * NTOK;
  int lane = threadIdx.x;
  int l31 = lane & 31, h5 = lane >> 5;

  // Q B-frags (col=q, k=d): aq[qb][slice]
  bf8_t aq[2][4];
  const unsigned short* qp = Qg + ((size_t)bh * NTOK + q0) * 64;
  #pragma unroll
  for (int qb = 0; qb < 2; ++qb)
    #pragma unroll
    for (int sl = 0; sl < 4; ++sl)
      aq[qb][sl] = *(const bf8_t*)(qp + (size_t)(qb * 32 + l31) * 64 + sl * 16 + h5 * 8);

  // staging sources: 4 K chunks + 4 V chunks per lane (8KB/tile), pre-swizzled global src
  const unsigned short* ksrc[4];
  const unsigned short* vsrc[4];
  #pragma unroll
  for (int i = 0; i < 4; ++i) {
    int c = i * 64 + lane;
    int kr = c >> 3, kc = (c & 7) ^ (kr & 7);
    ksrc[i] = kp + (size_t)(kvbase + kr) * 64 + kc * 8;
    int vr = c >> 2, vc = (c & 3) ^ ((vr >> 1) & 3);
    vsrc[i] = vp + (size_t)vr * NTOK + kvbase + vc * 8;
  }

#define STAGE(BUF) do { \
    _Pragma("unroll") \
    for (int i = 0; i < 4; ++i) { \
      gl_lds16(ksrc[i], &Kls[BUF][(i * 64 + lane) * 8]); \
      gl_lds16(vsrc[i], &Vls[BUF][(i * 64 + lane) * 8]); \
    } \
    _Pragma("unroll") \
    for (int i = 0; i < 4; ++i) { ksrc[i] += 32 * 64; vsrc[i] += 32; } \
  } while (0)

  f16v accO[2][2] = {};     // O^T[d][q]: [db][qb]
  float ls0 = 0.f, ls1 = 0.f;

  STAGE(0);
  STAGE(1);

#define BODY(CUR, DOSTAGE, LAST) do { \
    if (LAST) { WAITVM0(); } else { WAITVM8(); } \
    const unsigned short* Kc = Kls[CUR]; \
    const unsigned short* Vc = Vls[CUR]; \
    f16v sq0 = {}, sq1 = {}; \
    __builtin_amdgcn_s_setprio(1); \
    _Pragma("unroll") \
    for (int sl = 0; sl < 4; ++sl) { \
      bf8_t ak = ldsw128(Kc, l31, sl * 2 + h5); \
      sq0 = __builtin_amdgcn_mfma_f32_32x32x16_bf16(ak, aq[0][sl], sq0, 0, 0, 0); \
      sq1 = __builtin_amdgcn_mfma_f32_32x32x16_bf16(ak, aq[1][sl], sq1, 0, 0, 0); \
    } \
    __builtin_amdgcn_s_setprio(0); \
    float r0 = 0.f, r1 = 0.f; \
    _Pragma("unroll") \
    for (int r = 0; r < 16; ++r) { \
      float p0 = EXP2(sq0[r]); sq0[r] = p0; r0 += p0; \
      float p1 = EXP2(sq1[r]); sq1[r] = p1; r1 += p1; \
    } \
    ls0 += r0; ls1 += r1; \
    __builtin_amdgcn_s_setprio(1); \
    _Pragma("unroll") \
    for (int tp = 0; tp < 2; ++tp) { \
      unsigned int g0a0 = pkbf(sq0[8 * tp + 0], sq0[8 * tp + 1]); \
      unsigned int g0b0 = pkbf(sq0[8 * tp + 2], sq0[8 * tp + 3]); \
      unsigned int g1a0 = pkbf(sq0[8 * tp + 4], sq0[8 * tp + 5]); \
      unsigned int g1b0 = pkbf(sq0[8 * tp + 6], sq0[8 * tp + 7]); \
      unsigned int g0a1 = pkbf(sq1[8 * tp + 0], sq1[8 * tp + 1]); \
      unsigned int g0b1 = pkbf(sq1[8 * tp + 2], sq1[8 * tp + 3]); \
      unsigned int g1a1 = pkbf(sq1[8 * tp + 4], sq1[8 * tp + 5]); \
      unsigned int g1b1 = pkbf(sq1[8 * tp + 6], sq1[8 * tp + 7]); \
      unsigned int ra0 = __shfl_xor(h5 ? g0a0 : g1a0, 32); \
      unsigned int rb0 = __shfl_xor(h5 ? g0b0 : g1b0, 32); \
      unsigned int ra1 = __shfl_xor(h5 ? g0a1 : g1a1, 32); \
      unsigned int rb1 = __shfl_xor(h5 ? g0b1 : g1b1, 32); \
      union { unsigned int u[4]; bf8_t v; } p0, p1; \
      p0.u[0] = h5 ? ra0 : g0a0;  p0.u[1] = h5 ? rb0 : g0b0; \
      p0.u[2] = h5 ? g1a0 : ra0;  p0.u[3] = h5 ? g1b0 : rb0; \
      p1.u[0] = h5 ? ra1 : g0a1;  p1.u[1] = h5 ? rb1 : g0b1; \
      p1.u[2] = h5 ? g1a1 : ra1;  p1.u[3] = h5 ? g1b1 : rb1; \
      bf8_t av0 = ldsw64(Vc, l31, tp * 2 + h5); \
      bf8_t av1 = ldsw64(Vc, 32 + l31, tp * 2 + h5); \
      accO[0][0] = __builtin_amdgcn_mfma_f32_32x32x16_bf16(av0, p0.v, accO[0][0], 0, 0, 0); \
      accO[0][1] = __builtin_amdgcn_mfma_f32_32x32x16_bf16(av0, p1.v, accO[0][1], 0, 0, 0); \
      accO[1][0] = __builtin_amdgcn_mfma_f32_32x32x16_bf16(av1, p0.v, accO[1][0], 0, 0, 0); \
      accO[1][1] = __builtin_amdgcn_mfma_f32_32x32x16_bf16(av1, p1.v, accO[1][1], 0, 0, 0); \
    } \
    __builtin_amdgcn_s_setprio(0); \
    if (DOSTAGE) { LGKM0(); STAGE(CUR); } \
  } while (0)

  for (int tt = 0; tt < 31; ++tt) {
    BODY(0, 1, 0);
    BODY(1, 1, 0);
  }
  BODY(0, 0, 0);   // t=62
  BODY(1, 0, 1);   // t=63, drain

  // denominators: h5 halves hold disjoint kv partials for same q
  ls0 += __shfl_xor(ls0, 32);
  ls1 += __shfl_xor(ls1, 32);
  if (h5 == 0) {
    atomicAdd(&lsum[(size_t)bh * NTOK + q0 + l31], ls0);
    atomicAdd(&lsum[(size_t)bh * NTOK + q0 + 32 + l31], ls1);
  }
  // O partial -> bf16 pk atomics (exactly 2 contributors/location -> deterministic)
  #pragma unroll
  for (int db = 0; db < 2; ++db)
    #pragma unroll
    for (int qb = 0; qb < 2; ++qb) {
      int q = q0 + qb * 32 + l31;
      __hip_bfloat162* base = att + (size_t)(b * NTOK + q) * 256 + (h * 64 + db * 32 + 4 * h5) / 2;
      #pragma unroll
      for (int g = 0; g < 4; ++g) {
        unsafeAtomicAdd(base + 4 * g + 0, bf2(accO[db][qb][4 * g + 0], accO[db][qb][4 * g + 1]));
        unsafeAtomicAdd(base + 4 * g + 1, bf2(accO[db][qb][4 * g + 2], accO[db][qb][4 * g + 3]));
      }
    }
#undef BODY
#undef STAGE
}

// ---------------- normalize: att /= lsum ----------------
__global__ __launch_bounds__(256) void attn_norm(unsigned short* __restrict__ att,
                                                 const float* __restrict__ lsum) {
  int gid = blockIdx.x * 256 + threadIdx.x;   // 262144 threads, 16 ci each
  int row = gid >> 5;                          // b*4096 + n
  int ci0 = (gid & 31) * 16;
  int b = row >> 12, n = row & 4095;
  int h = ci0 >> 6;                            // uniform within the 16 ci
  float inv = 1.0f / lsum[(size_t)(b * 8 + h) * NTOK + n];
  unsigned short* p = att + (size_t)row * 512 + ci0;
  union { uint4 q; unsigned int u[4]; } v0, v1;
  v0.q = *(uint4*)p; v1.q = *(uint4*)(p + 8);
  #pragma unroll
  for (int w = 0; w < 4; ++w) {
    float lo = __uint_as_float(v0.u[w] << 16) * inv;
    float hi = __uint_as_float(v0.u[w] & 0xffff0000u) * inv;
    v0.u[w] = pkbf(lo, hi);
    float lo1 = __uint_as_float(v1.u[w] << 16) * inv;
    float hi1 = __uint_as_float(v1.u[w] & 0xffff0000u) * inv;
    v1.u[w] = pkbf(lo1, hi1);
  }
  *(uint4*)p = v0.q;
  *(uint4*)(p + 8) = v1.q;
}

// ---------------- out proj: M=256 K=512 N=4096, 64x64 tile (512 blocks), dbuf gload_lds ----------------
__global__ __launch_bounds__(256) void out_proj(const unsigned short* __restrict__ wo,
    const unsigned short* __restrict__ att, const float* __restrict__ bout,
    const float* __restrict__ x, float* __restrict__ y) {
  __shared__ unsigned short Al[2][2048];   // 64 x 32
  __shared__ unsigned short Bl[2][2048];   // 64 x 32
  int b = blockIdx.z, m0 = blockIdx.y * 64, n0 = blockIdx.x * 64;
  const unsigned short* Ap = wo + (size_t)m0 * 512;
  const unsigned short* Bp = att + ((size_t)b * NTOK + n0) * 512;
  int lane = threadIdx.x & 63, wv = threadIdx.x >> 6;
  int lq = lane & 15, hq = lane >> 4;
  int m_off = (wv >> 1) * 32, n_off = (wv & 1) * 32;
  int ck = threadIdx.x;
  int rr = ck >> 2, cu = ck & 3;
  int csw = (cu ^ ((rr >> 1) & 3)) << 3;
  f4_t acc[2][2] = {};
  {
    gl_lds16(Ap + (size_t)rr * 512 + csw, &Al[0][ck * 8]);
    gl_lds16(Bp + (size_t)rr * 512 + csw, &Bl[0][ck * 8]);
  }
  __syncthreads();
  for (int kt = 0; kt < 16; ++kt) {
    int cb = kt & 1, nb = cb ^ 1;
    if (kt < 15) {
      int k0 = (kt + 1) * 32;
      gl_lds16(Ap + (size_t)rr * 512 + k0 + csw, &Al[nb][ck * 8]);
      gl_lds16(Bp + (size_t)rr * 512 + k0 + csw, &Bl[nb][ck * 8]);
    }
    const unsigned short* Ac = Al[cb];
    const unsigned short* Bc = Bl[cb];
    bf8_t af[2], bfr[2];
    for (int i = 0; i < 2; ++i) af[i]  = ldsw64(Ac, m_off + i * 16 + lq, hq);
    for (int jj = 0; jj < 2; ++jj) bfr[jj] = ldsw64(Bc, n_off + jj * 16 + lq, hq);
    for (int i = 0; i < 2; ++i)
      for (int jj = 0; jj < 2; ++jj)
        acc[i][jj] = __builtin_amdgcn_mfma_f32_16x16x32_bf16(af[i], bfr[jj], acc[i][jj], 0, 0, 0);
    __syncthreads();
  }
  for (int i = 0; i < 2; ++i)
    for (int jj = 0; jj < 2; ++jj) {
      int n = n0 + n_off + jj * 16 + lq;
      for (int e = 0; e < 4; ++e) {
        int co = m0 + m_off + i * 16 + hq * 4 + e;
        size_t idx = ((size_t)b * 256 + co) * NTOK + n;
        y[idx] = acc[i][jj][e] + bout[co] + x[idx];
      }
    }
}

extern "C" void kernel_launch(void* const* d_in, const int* in_sizes, int n_in,
                              void* d_out, int out_size, void* d_ws, size_t ws_size,
                              hipStream_t stream) {
  const float* x     = (const float*)d_in[0];
  const float* gamma = (const float*)d_in[1];
  const float* beta  = (const float*)d_in[2];
  const float* wqkv  = (const float*)d_in[3];
  const float* bqkv  = (const float*)d_in[4];
  const float* wout  = (const float*)d_in[5];
  const float* bout  = (const float*)d_in[6];
  float* y = (float*)d_out;

  char* ws = (char*)d_ws;
  float*          stats = (float*)ws;                              // 128 B (pad 256)
  unsigned short* WQ    = (unsigned short*)(ws + 256);             // 786432
  unsigned short* WO    = (unsigned short*)(ws + 786688);          // 262144
  unsigned short* XNT   = (unsigned short*)(ws + 1048832);         // 4194304 (dead after qkv)
  float*          L     = (float*)(ws + 1048832);                  // 262144, reuses XNT region
  unsigned short* Qg    = (unsigned short*)(ws + 5243136);         // 8388608
  unsigned short* Kg    = (unsigned short*)(ws + 13631744);        // 8388608
  unsigned short* Vt    = (unsigned short*)(ws + 22020352);        // 8388608
  unsigned short* ATT   = (unsigned short*)(ws + 30408960);        // 8388608

  hipMemsetAsync(stats, 0, 128, stream);
  gn_stats_castw<<<768, 256, 0, stream>>>(x, stats, wqkv, wout, WQ, WO);
  gn_apply<<<dim3(64, 4, 2), 256, 0, stream>>>(x, gamma, beta, stats, XNT);
  qkv_gemm<<<dim3(32, 12, 2), 256, 0, stream>>>(WQ, XNT, bqkv, Qg, Kg, Vt);
  hipMemsetAsync(ATT, 0, 8388608, stream);   // after qkv: stream-ordered
  hipMemsetAsync(L, 0, 262144, stream);      // L overlaps XNT, dead by now
  attn<<<2048, 64, 0, stream>>>(Qg, Kg, Vt, (__hip_bfloat162*)ATT, L);
  attn_norm<<<1024, 256, 0, stream>>>(ATT, L);
  out_proj<<<dim3(64, 4, 2), 256, 0, stream>>>(WO, ATT, bout, x, y);
}

// Round 6
// 206.162 us; speedup vs baseline: 1.4547x; 1.4547x over previous
//
#include <hip/hip_runtime.h>
#include <hip/hip_bf16.h>

// AttentionBlock3D: GroupNorm(8,256) -> QKV 1x1 conv -> 8-head attn (n=4096, d=64) -> out proj -> +x
// R6: attn = 4-wave blocks (2 q-strips x 2 kv-halves), 32q/wave 32x32x16, register P-exchange,
//     per-half kv-32 dbuf LDS streams, block-internal LDS combine (no atomics, no norm pass).

typedef __attribute__((ext_vector_type(8))) short bf8_t;     // 8 bf16
typedef __attribute__((ext_vector_type(4))) float f4_t;      // 16x16 C/D frag
typedef __attribute__((ext_vector_type(16))) float f16v;     // 32x32 C/D frag

#define NTOK 4096
#define GRP_ELEMS (32 * 4096)

__device__ __forceinline__ unsigned short f2bf(float f) {
  union { float f; unsigned int i; } v; v.f = f;
  unsigned int r = v.i + 0x7fffu + ((v.i >> 16) & 1u);   // RNE
  return (unsigned short)(r >> 16);
}

__device__ __forceinline__ unsigned int pkbf(float a, float b) {
  float2 t; t.x = a; t.y = b;
  __hip_bfloat162 h = __float22bfloat162_rn(t);
  union { __hip_bfloat162 h; unsigned int u; } c; c.h = h;
  return c.u;
}

__device__ __forceinline__ void gl_lds16(const unsigned short* g, unsigned short* l) {
  __builtin_amdgcn_global_load_lds((const __attribute__((address_space(1))) void*)g,
                                   (__attribute__((address_space(3))) void*)l, 16, 0, 0);
}

// swizzled 16B LDS read; 128B-stride rows: slot ^= row&7
__device__ __forceinline__ bf8_t ldsw128(const unsigned short* base, int row, int du) {
  return *(const bf8_t*)((const char*)base + (((row << 7) + (du << 4)) ^ ((row & 7) << 4)));
}
// 64B-stride rows: slot ^= (row>>1)&3
__device__ __forceinline__ bf8_t ldsw64(const unsigned short* base, int row, int du) {
  return *(const bf8_t*)((const char*)base + (((row << 6) + (du << 4)) ^ (((row >> 1) & 3) << 4)));
}

#if __has_builtin(__builtin_amdgcn_exp2f)
#define EXP2 __builtin_amdgcn_exp2f
#else
#define EXP2 exp2f
#endif

// ---------------- GroupNorm stats (blocks 0..255) + weight cast (blocks 256..767) ----------------
__global__ __launch_bounds__(256) void gn_stats_castw(const float* __restrict__ x, float* __restrict__ stats,
    const float* __restrict__ wqkv, const float* __restrict__ wout,
    unsigned short* __restrict__ wq, unsigned short* __restrict__ wo) {
  int bid = blockIdx.x;
  if (bid >= 256) {
    int i = (bid - 256) * 256 + threadIdx.x;
    const float* src; unsigned short* dst; int off;
    if (i < 98304) { src = wqkv; dst = wq; off = i; }
    else           { src = wout; dst = wo; off = i - 98304; }
    float4 v = ((const float4*)src)[off];
    union { unsigned short s[4]; uint2 u; } o;
    o.s[0] = f2bf(v.x); o.s[1] = f2bf(v.y); o.s[2] = f2bf(v.z); o.s[3] = f2bf(v.w);
    *(uint2*)(dst + (size_t)off * 4) = o.u;
    return;
  }
  int g = bid & 15, sp = bid >> 4;
  const float4* p = (const float4*)(x + (size_t)g * GRP_ELEMS + (size_t)sp * 8192);
  float s = 0.f, s2 = 0.f;
  for (int i = threadIdx.x; i < 2048; i += 256) {
    float4 v = p[i];
    s  += v.x + v.y + v.z + v.w;
    s2 += v.x * v.x + v.y * v.y + v.z * v.z + v.w * v.w;
  }
  for (int m = 32; m; m >>= 1) { s += __shfl_xor(s, m); s2 += __shfl_xor(s2, m); }
  __shared__ float rs[4][2];
  int wv = threadIdx.x >> 6;
  if ((threadIdx.x & 63) == 0) { rs[wv][0] = s; rs[wv][1] = s2; }
  __syncthreads();
  if (threadIdx.x == 0) {
    float ts = rs[0][0] + rs[1][0] + rs[2][0] + rs[3][0];
    float t2 = rs[0][1] + rs[1][1] + rs[2][1] + rs[3][1];
    atomicAdd(&stats[g], ts);
    atomicAdd(&stats[16 + g], t2);
  }
}

// ---------------- GroupNorm apply + transpose to XN^T[b][n][c] bf16 ----------------
__global__ __launch_bounds__(256) void gn_apply(const float* __restrict__ x,
    const float* __restrict__ gamma, const float* __restrict__ beta,
    const float* __restrict__ stats, unsigned short* __restrict__ xnt) {
  __shared__ float t[64][65];
  int b = blockIdx.z, c0 = blockIdx.y * 64, n0 = blockIdx.x * 64;
  int tr = threadIdx.x >> 2;
  int tc = (threadIdx.x & 3) * 16;
  int c = c0 + tr;
  int g = b * 8 + (c >> 5);
  float mu = stats[g] * (1.f / GRP_ELEMS);
  float var = stats[16 + g] * (1.f / GRP_ELEMS) - mu * mu;
  float rstd = rsqrtf(var + 1e-5f);
  float sc = gamma[c] * rstd;
  float sh = beta[c] - mu * sc;
  const float* xp = x + ((size_t)(b * 256 + c)) * NTOK + n0 + tc;
  for (int q = 0; q < 4; ++q) {
    float4 v = *(const float4*)(xp + q * 4);
    t[tr][tc + q * 4 + 0] = v.x * sc + sh;
    t[tr][tc + q * 4 + 1] = v.y * sc + sh;
    t[tr][tc + q * 4 + 2] = v.z * sc + sh;
    t[tr][tc + q * 4 + 3] = v.w * sc + sh;
  }
  __syncthreads();
  int n = n0 + tr;
  union { unsigned short s[16]; uint4 u[2]; } tmp;
  for (int q = 0; q < 16; ++q) tmp.s[q] = f2bf(t[tc + q][tr]);
  uint4* dst = (uint4*)(xnt + ((size_t)b * NTOK + n) * 256 + c0 + tc);
  dst[0] = tmp.u[0];
  dst[1] = tmp.u[1];
}

// ---------------- QKV GEMM: M=1536 K=256 N=4096, 128x128 tile, BK=32, dbuf gload_lds ----------------
__global__ __launch_bounds__(256) void qkv_gemm(const unsigned short* __restrict__ wq,
    const unsigned short* __restrict__ xnt, const float* __restrict__ bqkv,
    unsigned short* __restrict__ Qg, unsigned short* __restrict__ Kg, unsigned short* __restrict__ Vt) {
  __shared__ unsigned short Al[2][4096];
  __shared__ unsigned short Bl[2][4096];
  int b = blockIdx.z, m0 = blockIdx.y * 128, n0 = blockIdx.x * 128;
  const unsigned short* Ap = wq + (size_t)m0 * 256;
  const unsigned short* Bp = xnt + ((size_t)b * NTOK + n0) * 256;
  int lane = threadIdx.x & 63, wv = threadIdx.x >> 6;
  int lq = lane & 15, hq = lane >> 4;
  int m_off = (wv >> 1) * 64, n_off = (wv & 1) * 64;
  f4_t acc[4][4] = {};
  {
    for (int is = 0; is < 2; ++is) {
      int ck = wv * 128 + is * 64 + lane;
      int r = ck >> 2, cu = ck & 3;
      int csw = (cu ^ ((r >> 1) & 3)) << 3;
      gl_lds16(Ap + (size_t)r * 256 + csw, &Al[0][(wv * 128 + is * 64) * 8]);
      gl_lds16(Bp + (size_t)r * 256 + csw, &Bl[0][(wv * 128 + is * 64) * 8]);
    }
  }
  __syncthreads();
  for (int kt = 0; kt < 8; ++kt) {
    int cb = kt & 1, nb = cb ^ 1;
    if (kt < 7) {
      int k0 = (kt + 1) * 32;
      for (int is = 0; is < 2; ++is) {
        int ck = wv * 128 + is * 64 + lane;
        int r = ck >> 2, cu = ck & 3;
        int csw = (cu ^ ((r >> 1) & 3)) << 3;
        gl_lds16(Ap + (size_t)r * 256 + k0 + csw, &Al[nb][(wv * 128 + is * 64) * 8]);
        gl_lds16(Bp + (size_t)r * 256 + k0 + csw, &Bl[nb][(wv * 128 + is * 64) * 8]);
      }
    }
    const unsigned short* Ac = Al[cb];
    const unsigned short* Bc = Bl[cb];
    bf8_t af[4], bfr[4];
    for (int i = 0; i < 4; ++i) af[i]  = ldsw64(Ac, m_off + i * 16 + lq, hq);
    for (int j = 0; j < 4; ++j) bfr[j] = ldsw64(Bc, n_off + j * 16 + lq, hq);
    for (int i = 0; i < 4; ++i)
      for (int j = 0; j < 4; ++j)
        acc[i][j] = __builtin_amdgcn_mfma_f32_16x16x32_bf16(af[i], bfr[j], acc[i][j], 0, 0, 0);
    __syncthreads();
  }
  int tq = m0 >> 9;   // block-uniform: 0=Q,1=K,2=V
  if (tq < 2) {
    unsigned short* dst = tq == 0 ? Qg : Kg;
    float sc = tq == 0 ? 0.1803368801111243f : 1.0f;  // 1/8 * log2(e) folded for exp2 softmax
    for (int i = 0; i < 4; ++i)
      for (int j = 0; j < 4; ++j) {
        int o0 = m0 + m_off + i * 16 + hq * 4;
        int n = n0 + n_off + j * 16 + lq;
        int h = (o0 >> 6) & 7, dd0 = o0 & 63;
        size_t bh = (size_t)b * 8 + h;
        uint2 pk;
        pk.x = pkbf((acc[i][j][0] + bqkv[o0 + 0]) * sc, (acc[i][j][1] + bqkv[o0 + 1]) * sc);
        pk.y = pkbf((acc[i][j][2] + bqkv[o0 + 2]) * sc, (acc[i][j][3] + bqkv[o0 + 3]) * sc);
        *(uint2*)(dst + (bh * NTOK + n) * 64 + dd0) = pk;
      }
  } else {
    for (int i = 0; i < 4; ++i)
      for (int j = 0; j < 4; ++j) {
        int n = n0 + n_off + j * 16 + lq;
        for (int jj = 0; jj < 4; ++jj) {
          int o = m0 + m_off + i * 16 + hq * 4 + jj;
          int h = (o >> 6) & 7, dd = o & 63;
          size_t bh = (size_t)b * 8 + h;
          Vt[(bh * 64 + dd) * NTOK + n] = f2bf(acc[i][j][jj] + bqkv[o]);  // V^T [d][n]
        }
      }
  }
}

// ---------------- Flash attention: 4 waves = 2 q-strips x 2 kv-halves, kv-tile 32, LDS combine ----------------
// grid 1024 (= 64 qt x 16 bh), 256 thr. LDS: K streams 16KB + V streams 16KB (combine area aliases).
__global__ __launch_bounds__(256, 4) void attn(const unsigned short* __restrict__ Qg,
    const unsigned short* __restrict__ Kg, const unsigned short* __restrict__ Vt,
    unsigned short* __restrict__ att) {
  __shared__ char smem[32768];
  int bid = blockIdx.x;
  // bid = inner*8 + xcd; xcd = bh>>1 (2 heads per XCD, 2MB K/V <= L2)
  int inner = bid >> 3;
  int bh = (bid & 7) * 2 + (inner & 1);
  int q0 = (inner >> 1) * 64;
  int b = bh >> 3, h = bh & 7;
  const unsigned short* kp = Kg + (size_t)bh * NTOK * 64;
  const unsigned short* vp = Vt + (size_t)bh * 64 * NTOK;
  int tid = threadIdx.x;
  int lane = tid & 63, wv = tid >> 6;
  int l31 = lane & 31, h5 = lane >> 5;
  int strip = wv & 1, half = wv >> 1;
  int kvbase = half * 2048;

  // Q B-frags: B[k=d][col=q=l31], d = sl*16 + h5*8 + e
  const unsigned short* qp = Qg + ((size_t)bh * NTOK + q0 + strip * 32 + l31) * 64;
  bf8_t aq[4];
  #pragma unroll
  for (int sl = 0; sl < 4; ++sl)
    aq[sl] = *(const bf8_t*)(qp + sl * 16 + h5 * 8);

  // LDS stream bases for this half
  unsigned short* Kb0 = (unsigned short*)(smem + half * 8192);            // buf stride 4096B = 2048 elems
  unsigned short* Vb0 = (unsigned short*)(smem + 16384 + half * 8192);

  // staging: 128 threads per half stage their half's 8KB tile: 2 K-chunks + 2 V-chunks each
  int t128 = tid & 127;
  int kr = t128 >> 3, kc = t128 & 7;
  int vr = t128 >> 2, vc = t128 & 3;
  const unsigned short* kSrc = kp + (size_t)(kvbase + kr) * 64 + ((kc ^ (kr & 7)) << 3);
  const unsigned short* vSrc = vp + (size_t)vr * NTOK + kvbase + ((vc ^ ((vr >> 1) & 3)) << 3);
  unsigned short* kDst0 = Kb0 + t128 * 8;   // chunk B at +1024 elems
  unsigned short* vDst0 = Vb0 + t128 * 8;

#define STAGE(BUF) do { \
    gl_lds16(kSrc,          kDst0 + (BUF) * 2048); \
    gl_lds16(kSrc + 1024,   kDst0 + (BUF) * 2048 + 1024); \
    gl_lds16(vSrc,          vDst0 + (BUF) * 2048); \
    gl_lds16(vSrc + 131072, vDst0 + (BUF) * 2048 + 1024); \
    kSrc += 2048; vSrc += 32; \
  } while (0)

  f16v accO[2] = {};   // O^T[d][q]: d = db*32 + (r&3)+8*(r>>2)+4*h5, q = l31
  float ls = 0.f;

#define COMPUTE(CB) do { \
    const unsigned short* Kc = Kb0 + (CB) * 2048; \
    const unsigned short* Vc = Vb0 + (CB) * 2048; \
    f16v s = {}; \
    __builtin_amdgcn_s_setprio(1); \
    _Pragma("unroll") \
    for (int sl = 0; sl < 4; ++sl) { \
      bf8_t ak = ldsw128(Kc, l31, sl * 2 + h5); \
      s = __builtin_amdgcn_mfma_f32_32x32x16_bf16(ak, aq[sl], s, 0, 0, 0); \
    } \
    __builtin_amdgcn_s_setprio(0); \
    float rs = 0.f; \
    _Pragma("unroll") \
    for (int r = 0; r < 16; ++r) { float p = EXP2(s[r]); s[r] = p; rs += p; } \
    ls += rs; \
    _Pragma("unroll") \
    for (int tp = 0; tp < 2; ++tp) { \
      unsigned int g0a = pkbf(s[8 * tp + 0], s[8 * tp + 1]); \
      unsigned int g0b = pkbf(s[8 * tp + 2], s[8 * tp + 3]); \
      unsigned int g1a = pkbf(s[8 * tp + 4], s[8 * tp + 5]); \
      unsigned int g1b = pkbf(s[8 * tp + 6], s[8 * tp + 7]); \
      unsigned int ra = __shfl_xor(h5 ? g0a : g1a, 32); \
      unsigned int rb = __shfl_xor(h5 ? g0b : g1b, 32); \
      union { unsigned int u[4]; bf8_t v; } pb; \
      pb.u[0] = h5 ? ra : g0a;  pb.u[1] = h5 ? rb : g0b; \
      pb.u[2] = h5 ? g1a : ra;  pb.u[3] = h5 ? g1b : rb; \
      bf8_t av0 = ldsw64(Vc, l31, tp * 2 + h5); \
      bf8_t av1 = ldsw64(Vc, 32 + l31, tp * 2 + h5); \
      __builtin_amdgcn_s_setprio(1); \
      accO[0] = __builtin_amdgcn_mfma_f32_32x32x16_bf16(av0, pb.v, accO[0], 0, 0, 0); \
      accO[1] = __builtin_amdgcn_mfma_f32_32x32x16_bf16(av1, pb.v, accO[1], 0, 0, 0); \
      __builtin_amdgcn_s_setprio(0); \
    } \
  } while (0)

  STAGE(0);
  __syncthreads();
  for (int tt = 0; tt < 31; ++tt) {
    STAGE(1); COMPUTE(0); __syncthreads();
    STAGE(0); COMPUTE(1); __syncthreads();
  }
  STAGE(1); COMPUTE(0); __syncthreads();
  COMPUTE(1); __syncthreads();

  // half-denominator for q = q0+strip*32+l31 (duplicated across h5 after reduce)
  ls += __shfl_xor(ls, 32);

  // block-internal combine across kv-halves via LDS (K/V streams dead now)
  float* cbuf = (float*)(smem);                 // per strip: 64 lanes x 144B (pad to de-bank)
  float* lbuf = (float*)(smem + 18432);         // [2][64]
  if (half == 1) {
    float* dst = cbuf + strip * 2304 + lane * 36;   // 2304 floats = 9216B ; 36 floats = 144B
    #pragma unroll
    for (int db = 0; db < 2; ++db)
      #pragma unroll
      for (int g = 0; g < 4; ++g) {
        float4 v; v.x = accO[db][4 * g + 0]; v.y = accO[db][4 * g + 1];
        v.z = accO[db][4 * g + 2]; v.w = accO[db][4 * g + 3];
        *(float4*)(dst + (db * 4 + g) * 4) = v;
      }
    lbuf[strip * 64 + lane] = ls;
  }
  __syncthreads();
  if (half == 0) {
    const float* src = cbuf + strip * 2304 + lane * 36;
    float lt = ls + lbuf[strip * 64 + lane];
    float inv = 1.0f / lt;
    int q = q0 + strip * 32 + l31;
    unsigned short* op = att + ((size_t)b * NTOK + q) * 512 + h * 64;
    #pragma unroll
    for (int db = 0; db < 2; ++db)
      #pragma unroll
      for (int g = 0; g < 4; ++g) {
        float4 v = *(const float4*)(src + (db * 4 + g) * 4);
        uint2 pk;
        pk.x = pkbf((accO[db][4 * g + 0] + v.x) * inv, (accO[db][4 * g + 1] + v.y) * inv);
        pk.y = pkbf((accO[db][4 * g + 2] + v.z) * inv, (accO[db][4 * g + 3] + v.w) * inv);
        *(uint2*)(op + db * 32 + g * 8 + h5 * 4) = pk;
      }
  }
#undef COMPUTE
#undef STAGE
}

// ---------------- out proj: M=256 K=512 N=4096, 64x64 tile (512 blocks), dbuf gload_lds ----------------
__global__ __launch_bounds__(256) void out_proj(const unsigned short* __restrict__ wo,
    const unsigned short* __restrict__ att, const float* __restrict__ bout,
    const float* __restrict__ x, float* __restrict__ y) {
  __shared__ unsigned short Al[2][2048];   // 64 x 32
  __shared__ unsigned short Bl[2][2048];   // 64 x 32
  int b = blockIdx.z, m0 = blockIdx.y * 64, n0 = blockIdx.x * 64;
  const unsigned short* Ap = wo + (size_t)m0 * 512;
  const unsigned short* Bp = att + ((size_t)b * NTOK + n0) * 512;
  int lane = threadIdx.x & 63, wv = threadIdx.x >> 6;
  int lq = lane & 15, hq = lane >> 4;
  int m_off = (wv >> 1) * 32, n_off = (wv & 1) * 32;
  int ck = threadIdx.x;
  int rr = ck >> 2, cu = ck & 3;
  int csw = (cu ^ ((rr >> 1) & 3)) << 3;
  f4_t acc[2][2] = {};
  {
    gl_lds16(Ap + (size_t)rr * 512 + csw, &Al[0][ck * 8]);
    gl_lds16(Bp + (size_t)rr * 512 + csw, &Bl[0][ck * 8]);
  }
  __syncthreads();
  for (int kt = 0; kt < 16; ++kt) {
    int cb = kt & 1, nb = cb ^ 1;
    if (kt < 15) {
      int k0 = (kt + 1) * 32;
      gl_lds16(Ap + (size_t)rr * 512 + k0 + csw, &Al[nb][ck * 8]);
      gl_lds16(Bp + (size_t)rr * 512 + k0 + csw, &Bl[nb][ck * 8]);
    }
    const unsigned short* Ac = Al[cb];
    const unsigned short* Bc = Bl[cb];
    bf8_t af[2], bfr[2];
    for (int i = 0; i < 2; ++i) af[i]  = ldsw64(Ac, m_off + i * 16 + lq, hq);
    for (int jj = 0; jj < 2; ++jj) bfr[jj] = ldsw64(Bc, n_off + jj * 16 + lq, hq);
    for (int i = 0; i < 2; ++i)
      for (int jj = 0; jj < 2; ++jj)
        acc[i][jj] = __builtin_amdgcn_mfma_f32_16x16x32_bf16(af[i], bfr[jj], acc[i][jj], 0, 0, 0);
    __syncthreads();
  }
  for (int i = 0; i < 2; ++i)
    for (int jj = 0; jj < 2; ++jj) {
      int n = n0 + n_off + jj * 16 + lq;
      for (int e = 0; e < 4; ++e) {
        int co = m0 + m_off + i * 16 + hq * 4 + e;
        size_t idx = ((size_t)b * 256 + co) * NTOK + n;
        y[idx] = acc[i][jj][e] + bout[co] + x[idx];
      }
    }
}

extern "C" void kernel_launch(void* const* d_in, const int* in_sizes, int n_in,
                              void* d_out, int out_size, void* d_ws, size_t ws_size,
                              hipStream_t stream) {
  const float* x     = (const float*)d_in[0];
  const float* gamma = (const float*)d_in[1];
  const float* beta  = (const float*)d_in[2];
  const float* wqkv  = (const float*)d_in[3];
  const float* bqkv  = (const float*)d_in[4];
  const float* wout  = (const float*)d_in[5];
  const float* bout  = (const float*)d_in[6];
  float* y = (float*)d_out;

  char* ws = (char*)d_ws;
  float*          stats = (float*)ws;                              // 128 B (pad 256)
  unsigned short* WQ    = (unsigned short*)(ws + 256);             // 786432
  unsigned short* WO    = (unsigned short*)(ws + 786688);          // 262144
  unsigned short* XNT   = (unsigned short*)(ws + 1048832);         // 4194304
  unsigned short* Qg    = (unsigned short*)(ws + 5243136);         // 8388608
  unsigned short* Kg    = (unsigned short*)(ws + 13631744);        // 8388608
  unsigned short* Vt    = (unsigned short*)(ws + 22020352);        // 8388608
  unsigned short* ATT   = (unsigned short*)(ws + 30408960);        // 8388608

  hipMemsetAsync(stats, 0, 128, stream);
  gn_stats_castw<<<768, 256, 0, stream>>>(x, stats, wqkv, wout, WQ, WO);
  gn_apply<<<dim3(64, 4, 2), 256, 0, stream>>>(x, gamma, beta, stats, XNT);
  qkv_gemm<<<dim3(32, 12, 2), 256, 0, stream>>>(WQ, XNT, bqkv, Qg, Kg, Vt);
  attn<<<1024, 256, 0, stream>>>(Qg, Kg, Vt, ATT);
  out_proj<<<dim3(64, 4, 2), 256, 0, stream>>>(WO, ATT, bout, x, y);
}